// Round 1
// 62214.148 us; speedup vs baseline: 1.1374x; 1.1374x over previous
//
#include <hip/hip_runtime.h>

typedef unsigned int u32;
typedef unsigned short u16;
typedef _Float16 f16;
typedef _Float16 f16x2 __attribute__((ext_vector_type(2)));

#define T_SEQ 32768

// ---------------- ws layout (bytes) ----------------
static const size_t OFF_DT   = 0;         // u32 dtype flag (1 = f32 inputs)
static const size_t OFF_FLG  = 1024;      // u32[128] (legacy, kept zeroed)
static const size_t OFF_MAP  = 4096;      // int [T]
static const size_t OFF_H1G  = 135168;    // f16 [1024][512]
static const size_t OFF_BIAS = 1183744;   // f32 [4][1024]
static const size_t OFF_FCW  = 1200128;   // f32 [512*64]
static const size_t OFF_WQ8  = 1331200;   // u32 [4][1024][64] int8 W_hh (1 MB)
static const size_t OFF_WIH0 = 3428352;   // u32 [2][1024][32]
static const size_t OFF_WIH1 = 3690496;   // u32 [2][1024][256]
static const size_t OFF_XQ   = 5787648;   // u32 [T][32]
static const size_t OFF_H0   = 9981952;   // f16 [T][512]
static const size_t OFF_XG   = 43536384;  // f16 [ndir][T][1024], LAST (adaptive)
static const size_t XG_DIR   = (size_t)T_SEQ * 1024 * 2;  // 67108864 bytes
static const size_t NEED_PAR = OFF_XG + 2 * XG_DIR;       // 177754112

// ---------------- helpers ----------------
__device__ __forceinline__ float bf2f(u16 u) {
  union { u32 i; float f; } v; v.i = ((u32)u) << 16; return v.f;
}
__device__ __forceinline__ u16 f2bf(float f) {
  union { float f; u32 i; } v; v.f = f;
  u32 u = v.i;
  return (u16)((u + 0x7fffu + ((u >> 16) & 1u)) >> 16);
}
__device__ __forceinline__ u32 packf2(float a, float b) {
  f16x2 p; p.x = (f16)a; p.y = (f16)b;
  return __builtin_bit_cast(u32, p);
}
__device__ __forceinline__ u32 bf2f2(u32 v) {  // two bf16 -> two f16
  union { u32 i; float f; } lo, hi;
  lo.i = v << 16; hi.i = v & 0xffff0000u;
  return packf2(lo.f, hi.f);
}
__device__ __forceinline__ float ldf(const void* p, size_t i, u32 isf) {
  return isf ? ((const float*)p)[i] : bf2f(((const u16*)p)[i]);
}
__device__ __forceinline__ float fdot2f(f16x2 a, f16x2 b, float c) {
#if __has_builtin(__builtin_amdgcn_fdot2)
  return __builtin_amdgcn_fdot2(a, b, c, false);
#else
  return c + (float)a.x * (float)b.x + (float)a.y * (float)b.y;
#endif
}
__device__ __forceinline__ float fdotu(u32 a, u32 b, float c) {
  return fdot2f(__builtin_bit_cast(f16x2, a), __builtin_bit_cast(f16x2, b), c);
}
__device__ __forceinline__ int sdot4(u32 a, u32 b, int c) {
#if __has_builtin(__builtin_amdgcn_sdot4)
  return __builtin_amdgcn_sdot4((int)a, (int)b, c, false);
#else
  int r = c;
#pragma unroll
  for (int j = 0; j < 4; ++j)
    r += (int)(signed char)(a >> (8 * j)) * (int)(signed char)(b >> (8 * j));
  return r;
#endif
}
// lane pair swap (lanes 2u <-> 2u+1) via DPP quad_perm [1,0,3,2] — pure VALU,
// replaces a ds_bpermute-based __shfl_xor on the critical path.
__device__ __forceinline__ int dpp_xor1(int x) {
#if __has_builtin(__builtin_amdgcn_update_dpp)
  return __builtin_amdgcn_update_dpp(0, x, 0xB1, 0xF, 0xF, true);
#else
  return __shfl_xor(x, 1);
#endif
}
__device__ __forceinline__ float sigf(float x) {
  return __builtin_amdgcn_rcpf(1.0f + __builtin_amdgcn_exp2f(-1.4426950408889634f * x));
}
__device__ __forceinline__ float tanhf_fast(float x) {
  return 1.0f - 2.0f * __builtin_amdgcn_rcpf(1.0f + __builtin_amdgcn_exp2f(2.8853900817779268f * x));
}

// ---------------- dtype detection ----------------
__global__ void k_detect(const u16* __restrict__ probe, u32* __restrict__ dt) {
  __shared__ int cnt;
  if (threadIdx.x == 0) cnt = 0;
  __syncthreads();
  int bad = 0;
  for (int i = threadIdx.x; i < 8192; i += 256) {
    float v = bf2f(probe[i]);
    if (!(v * v <= 16.0f)) bad++;
  }
  atomicAdd(&cnt, bad);
  __syncthreads();
  if (threadIdx.x == 0) *dt = (cnt > 64) ? 1u : 0u;
}

// ---------------- conversions ----------------
__global__ void k_conv_pairs(const void* __restrict__ src, u32* __restrict__ dst,
                             int np, const u32* __restrict__ dtp) {
  u32 isf = *dtp;
  int i = blockIdx.x * 256 + threadIdx.x;
  if (i >= np) return;
  if (isf) {
    const float* s = (const float*)src;
    dst[i] = packf2(s[2 * i], s[2 * i + 1]);
  } else {
    dst[i] = bf2f2(((const u32*)src)[i]);
  }
}

// int8-quantize one W_hh matrix [1024][256] -> u32 [1024][64], scale 2048
__global__ void k_quant(const void* __restrict__ src, u32* __restrict__ dst,
                        const u32* __restrict__ dtp) {
  u32 isf = *dtp;
  int i = blockIdx.x * 256 + threadIdx.x;  // 65536
  int row = i >> 6, c = i & 63;
  u32 out = 0;
#pragma unroll
  for (int j = 0; j < 4; ++j) {
    float w = ldf(src, (size_t)row * 256 + 4 * c + j, isf);
    int q = (int)rintf(w * 2048.0f);
    q = q > 127 ? 127 : (q < -127 ? -127 : q);
    out |= ((u32)(q & 0xff)) << (8 * j);
  }
  dst[i] = out;
}

__global__ void k_conv_misc(const void* bi0f, const void* bh0f, const void* bi0b, const void* bh0b,
                            const void* bi1f, const void* bh1f, const void* bi1b, const void* bh1b,
                            const void* fcb, float* __restrict__ bias, float* __restrict__ fcw,
                            u32* __restrict__ flags, int* __restrict__ map,
                            const u32* __restrict__ dtp) {
  u32 isf = *dtp;
  int i = blockIdx.x * 256 + threadIdx.x;
  if (i < 4096) {
    int ld = i >> 10, r = i & 1023;
    const void* bi; const void* bh;
    if (ld == 0)      { bi = bi0f; bh = bh0f; }
    else if (ld == 1) { bi = bi0b; bh = bh0b; }
    else if (ld == 2) { bi = bi1f; bh = bh1f; }
    else              { bi = bi1b; bh = bh1b; }
    bias[i] = ldf(bi, r, isf) + ldf(bh, r, isf);
  } else if (i < 36864) {
    fcw[i - 4096] = ldf(fcb, i - 4096, isf);
  } else if (i < 36992) {
    flags[i - 36864] = 0;
  } else if (i < 69760) {
    map[i - 36992] = -1;
  }
}

__global__ void k_conv_x(const void* __restrict__ Y, const void* __restrict__ dT,
                         u32* __restrict__ xq, const u32* __restrict__ dtp) {
  u32 isf = *dtp;
  int i = blockIdx.x * 256 + threadIdx.x;  // T*32
  if (i >= T_SEQ * 32) return;
  int t = i >> 5, m = i & 31, k2 = 2 * m;
  float a = ldf(Y, (size_t)t * 63 + k2, isf);
  float b = (k2 + 1 < 63) ? ldf(Y, (size_t)t * 63 + k2 + 1, isf) : ldf(dT, t, isf);
  xq[i] = packf2(a, b);
}

__global__ void k_map_set(const int* __restrict__ idx, int* __restrict__ map) {
  int i = blockIdx.x * 256 + threadIdx.x;
  if (i < 1024) map[idx[i]] = i;
}

// ---------------- input-projection GEMM ----------------
__global__ __launch_bounds__(256) void k_gemm(
    const u32* __restrict__ Aq, const u32* __restrict__ Wc,
    const float* __restrict__ bias, f16* __restrict__ xg_slot, int Kp) {
  int t0 = blockIdx.x << 6, r0 = blockIdx.y << 6;
  int tid = threadIdx.x, tx = tid & 15, ty = tid >> 4;
  __shared__ u32 As[64][33];
  __shared__ u32 Bs[64][33];
  float acc[4][4] = {};
  for (int kp0 = 0; kp0 < Kp; kp0 += 32) {
#pragma unroll
    for (int i = 0; i < 8; ++i) {
      int idx = tid + (i << 8);
      int row = idx >> 5, kp = idx & 31, kpg = kp0 + kp;
      As[row][kp] = Aq[(size_t)(t0 + row) * Kp + kpg];
      Bs[row][kp] = Wc[(size_t)(r0 + row) * Kp + kpg];
    }
    __syncthreads();
#pragma unroll 4
    for (int kk = 0; kk < 32; ++kk) {
      u32 av[4], bv[4];
#pragma unroll
      for (int i = 0; i < 4; ++i) av[i] = As[ty * 4 + i][kk];
#pragma unroll
      for (int i = 0; i < 4; ++i) bv[i] = Bs[tx * 4 + i][kk];
#pragma unroll
      for (int i = 0; i < 4; ++i)
#pragma unroll
        for (int j = 0; j < 4; ++j)
          acc[i][j] = fdotu(av[i], bv[j], acc[i][j]);
    }
    __syncthreads();
  }
#pragma unroll
  for (int i = 0; i < 4; ++i) {
    int t = t0 + ty * 4 + i;
#pragma unroll
    for (int j = 0; j < 4; ++j) {
      int r = r0 + tx * 4 + j;
      xg_slot[(size_t)t * 1024 + r] = (f16)(acc[i][j] + bias[r]);
    }
  }
}

// ---------------- recurrence: int8 weights, ONE workgroup per direction ------
// 512 threads, thread PAIR (lanes 2u, 2u+1) owns hidden unit u:
//   lane 2u   : K in [0,128)   for all 4 gate rows (u, 256+u, 512+u, 768+u)
//   lane 2u+1 : K in [128,256) for the same 4 rows
// Weights: 4 gates x 32 u32 = 128 VGPRs/thread, all pinned in arch VGPRs
// (__launch_bounds__(512,2) -> 256-VGPR budget; NO AGPR shuffling, NO LDS
// weight streaming). Partial sums combine with one DPP xor-1 per gate
// (integer add -> bit-identical to the unsplit dot). Both lanes redundantly
// compute the activations, so there is NO gate exchange through LDS, no
// divergent tid<256 phase, and only ONE barrier per step (double-buffered
// 2x256B h-buffer; byte-granular LDS writes from even lanes).
__global__ __launch_bounds__(512, 2) void k_recur2(
    const f16* __restrict__ xg, const u32* __restrict__ wq,
    f16* __restrict__ h_full, f16* __restrict__ h1g,
    const int* __restrict__ map, int dir0) {
  const int dir = dir0 + blockIdx.x;
  const int tid = threadIdx.x;
  const int u = tid >> 1;    // hidden unit owned by this pair
  const int half = tid & 1;  // K half
  const u32* wqd = wq + ((size_t)dir << 16);  // [1024][64]

  __shared__ __align__(16) unsigned char hb8[2][256];  // double-buffered h (i8)

  u32 w0[32], w1[32], w2[32], w3[32];
  {
    const u32* p0 = wqd + ((size_t)(0 * 256 + u) << 6) + (half << 5);
    const u32* p1 = wqd + ((size_t)(1 * 256 + u) << 6) + (half << 5);
    const u32* p2 = wqd + ((size_t)(2 * 256 + u) << 6) + (half << 5);
    const u32* p3 = wqd + ((size_t)(3 * 256 + u) << 6) + (half << 5);
#pragma unroll
    for (int i = 0; i < 32; ++i) {
      w0[i] = p0[i]; w1[i] = p1[i]; w2[i] = p2[i]; w3[i] = p3[i];
    }
  }
  // Pin weights in arch VGPRs (blocks rematerialization / AGPR demotion).
#pragma unroll
  for (int i = 0; i < 32; ++i)
    asm volatile("" : "+v"(w0[i]), "+v"(w1[i]), "+v"(w2[i]), "+v"(w3[i]));

  if (tid < 128) ((u32*)hb8)[tid] = 0;

  float c_state = 0.f;
  const f16* xg_d = xg + ((size_t)blockIdx.x * T_SEQ * 1024);
  const float ksc = 1.0f / (2048.0f * 127.0f);

  int t = dir ? (T_SEQ - 1) : 0;
  float xa0 = (float)xg_d[(size_t)t * 1024 + u];
  float xa1 = (float)xg_d[(size_t)t * 1024 + 256 + u];
  float xa2 = (float)xg_d[(size_t)t * 1024 + 512 + u];
  float xa3 = (float)xg_d[(size_t)t * 1024 + 768 + u];
  int mp = map ? map[t] : -1;

  int p = 0;
  __syncthreads();  // hb8[0] zeroed

  for (int step = 0; step < T_SEQ; ++step) {
    float xb0 = xa0, xb1 = xa1, xb2 = xa2, xb3 = xa3;
    int ms = mp;
    const int tn = dir ? (T_SEQ - 2 - step) : (step + 1);
    if (step + 1 < T_SEQ) {  // prefetch next xg + map (wave-uniform branch)
      xa0 = (float)xg_d[(size_t)tn * 1024 + u];
      xa1 = (float)xg_d[(size_t)tn * 1024 + 256 + u];
      xa2 = (float)xg_d[(size_t)tn * 1024 + 512 + u];
      xa3 = (float)xg_d[(size_t)tn * 1024 + 768 + u];
      if (map) mp = map[tn];
    }
    int acc0 = 0, acc1 = 0, acc2 = 0, acc3 = 0;
    const uint4* hp = (const uint4*)(&hb8[p][0]) + (half << 3);
#pragma unroll
    for (int c = 0; c < 8; ++c) {
      uint4 hv = hp[c];
      acc0 = sdot4(w0[4 * c + 0], hv.x, acc0);
      acc1 = sdot4(w1[4 * c + 0], hv.x, acc1);
      acc2 = sdot4(w2[4 * c + 0], hv.x, acc2);
      acc3 = sdot4(w3[4 * c + 0], hv.x, acc3);
      acc0 = sdot4(w0[4 * c + 1], hv.y, acc0);
      acc1 = sdot4(w1[4 * c + 1], hv.y, acc1);
      acc2 = sdot4(w2[4 * c + 1], hv.y, acc2);
      acc3 = sdot4(w3[4 * c + 1], hv.y, acc3);
      acc0 = sdot4(w0[4 * c + 2], hv.z, acc0);
      acc1 = sdot4(w1[4 * c + 2], hv.z, acc1);
      acc2 = sdot4(w2[4 * c + 2], hv.z, acc2);
      acc3 = sdot4(w3[4 * c + 2], hv.z, acc3);
      acc0 = sdot4(w0[4 * c + 3], hv.w, acc0);
      acc1 = sdot4(w1[4 * c + 3], hv.w, acc1);
      acc2 = sdot4(w2[4 * c + 3], hv.w, acc2);
      acc3 = sdot4(w3[4 * c + 3], hv.w, acc3);
    }
    // combine K-halves across the lane pair (exact integer add)
    acc0 += dpp_xor1(acc0);
    acc1 += dpp_xor1(acc1);
    acc2 += dpp_xor1(acc2);
    acc3 += dpp_xor1(acc3);
    float gi = sigf(xb0 + (float)acc0 * ksc);
    float gf = sigf(xb1 + (float)acc1 * ksc);
    float gg = tanhf_fast(xb2 + (float)acc2 * ksc);
    float go = sigf(xb3 + (float)acc3 * ksc);
    c_state = gf * c_state + gi * gg;
    float h = go * tanhf_fast(c_state);
    int q = (int)rintf(h * 127.0f);
    if (!half) {
      hb8[p ^ 1][u] = (unsigned char)(q & 0xff);
      if (h_full) h_full[(size_t)t * 512 + (dir << 8) + u] = (f16)h;
      if (h1g && ms >= 0) h1g[(size_t)ms * 512 + (dir << 8) + u] = (f16)h;
    }
    __syncthreads();  // writes to hb8[p^1] visible; all reads of hb8[p] done
    p ^= 1;
    t = tn;
  }
}

// ---------------- FC + gather ----------------
__global__ void k_fc(const f16* __restrict__ h1g, const int* __restrict__ map,
                     const int* __restrict__ idx, const float* __restrict__ fcw,
                     void* __restrict__ out, const u32* __restrict__ dtp) {
  u32 isf = *dtp;
  int n = blockIdx.x;
  int cc = threadIdx.x;  // 64
  int slot = map[idx[n]];
  const f16* hp = h1g + (size_t)slot * 512;
  float acc = 0.f;
#pragma unroll 8
  for (int k = 0; k < 512; ++k) acc += (float)hp[k] * fcw[k * 64 + cc];
  int o = (cc < 32) ? (n * 32 + cc) : (32 * 1024 + n * 32 + (cc - 32));
  if (isf) ((float*)out)[o] = acc;
  else     ((u16*)out)[o]   = f2bf(acc);
}

// ---------------- launch ----------------
extern "C" void kernel_launch(void* const* d_in, const int* in_sizes, int n_in,
                              void* d_out, int out_size, void* d_ws, size_t ws_size,
                              hipStream_t stream) {
  const void* Y        = d_in[0];
  const void* dT       = d_in[1];
  const int*  idx      = (const int*)d_in[2];
  const void* w_ih_l0f = d_in[3];
  const void* w_hh_l0f = d_in[4];
  const void* b_ih_l0f = d_in[5];
  const void* b_hh_l0f = d_in[6];
  const void* w_ih_l0b = d_in[7];
  const void* w_hh_l0b = d_in[8];
  const void* b_ih_l0b = d_in[9];
  const void* b_hh_l0b = d_in[10];
  const void* w_ih_l1f = d_in[11];
  const void* w_hh_l1f = d_in[12];
  const void* b_ih_l1f = d_in[13];
  const void* b_hh_l1f = d_in[14];
  const void* w_ih_l1b = d_in[15];
  const void* w_hh_l1b = d_in[16];
  const void* b_ih_l1b = d_in[17];
  const void* b_hh_l1b = d_in[18];
  const void* fcbf     = d_in[19];

  char* ws = (char*)d_ws;
  u32*  dt    = (u32*)(ws + OFF_DT);
  u32*  flags = (u32*)(ws + OFF_FLG);
  int*  map   = (int*)(ws + OFF_MAP);
  f16*  h1g   = (f16*)(ws + OFF_H1G);
  float* bias = (float*)(ws + OFF_BIAS);
  float* fcw  = (float*)(ws + OFF_FCW);
  u32*  wq8   = (u32*)(ws + OFF_WQ8);
  u32*  wih0  = (u32*)(ws + OFF_WIH0);
  u32*  wih1  = (u32*)(ws + OFF_WIH1);
  u32*  xq    = (u32*)(ws + OFF_XQ);
  f16*  h0    = (f16*)(ws + OFF_H0);
  f16*  xg    = (f16*)(ws + OFF_XG);
  f16*  xg1   = xg + XG_DIR / 2;  // f16 elements

  const int par = (ws_size >= NEED_PAR) ? 1 : 0;

  k_detect<<<1, 256, 0, stream>>>((const u16*)w_hh_l0f, dt);
  k_quant<<<256, 256, 0, stream>>>(w_hh_l0f, wq8 + 0 * 65536, dt);
  k_quant<<<256, 256, 0, stream>>>(w_hh_l0b, wq8 + 1 * 65536, dt);
  k_quant<<<256, 256, 0, stream>>>(w_hh_l1f, wq8 + 2 * 65536, dt);
  k_quant<<<256, 256, 0, stream>>>(w_hh_l1b, wq8 + 3 * 65536, dt);
  k_conv_pairs<<<128, 256, 0, stream>>>(w_ih_l0f, wih0 + 0, 32768, dt);
  k_conv_pairs<<<128, 256, 0, stream>>>(w_ih_l0b, wih0 + 32768, 32768, dt);
  k_conv_pairs<<<1024, 256, 0, stream>>>(w_ih_l1f, wih1 + 0, 262144, dt);
  k_conv_pairs<<<1024, 256, 0, stream>>>(w_ih_l1b, wih1 + 262144, 262144, dt);
  k_conv_misc<<<273, 256, 0, stream>>>(b_ih_l0f, b_hh_l0f, b_ih_l0b, b_hh_l0b,
                                       b_ih_l1f, b_hh_l1f, b_ih_l1b, b_hh_l1b,
                                       fcbf, bias, fcw, flags, map, dt);
  k_conv_x<<<4096, 256, 0, stream>>>(Y, dT, xq, dt);
  k_map_set<<<4, 256, 0, stream>>>(idx, map);

  dim3 ggrid(T_SEQ / 64, 16);
  if (par) {
    k_gemm<<<ggrid, 256, 0, stream>>>(xq, wih0, bias, xg, 32);
    k_gemm<<<ggrid, 256, 0, stream>>>(xq, wih0 + 32768, bias + 1024, xg1, 32);
    k_recur2<<<2, 512, 0, stream>>>(xg, wq8, h0, nullptr, nullptr, 0);
    k_gemm<<<ggrid, 256, 0, stream>>>((const u32*)h0, wih1, bias + 2048, xg, 256);
    k_gemm<<<ggrid, 256, 0, stream>>>((const u32*)h0, wih1 + 262144, bias + 3072, xg1, 256);
    k_recur2<<<2, 512, 0, stream>>>(xg, wq8 + 2 * 65536, nullptr, h1g, map, 0);
  } else {
    k_gemm<<<ggrid, 256, 0, stream>>>(xq, wih0, bias, xg, 32);
    k_recur2<<<1, 512, 0, stream>>>(xg, wq8, h0, nullptr, nullptr, 0);
    k_gemm<<<ggrid, 256, 0, stream>>>(xq, wih0 + 32768, bias + 1024, xg, 32);
    k_recur2<<<1, 512, 0, stream>>>(xg, wq8, h0, nullptr, nullptr, 1);
    k_gemm<<<ggrid, 256, 0, stream>>>((const u32*)h0, wih1, bias + 2048, xg, 256);
    k_recur2<<<1, 512, 0, stream>>>(xg, wq8 + 2 * 65536, nullptr, h1g, map, 0);
    k_gemm<<<ggrid, 256, 0, stream>>>((const u32*)h0, wih1 + 262144, bias + 3072, xg, 256);
    k_recur2<<<1, 512, 0, stream>>>(xg, wq8 + 2 * 65536, nullptr, h1g, map, 1);
  }
  k_fc<<<1024, 64, 0, stream>>>(h1g, map, idx, fcw, d_out, dt);
}